// Round 2
// baseline (732.040 us; speedup 1.0000x reference)
//
#include <hip/hip_runtime.h>
#include <hip/hip_bf16.h>

#define B_TOT   2048      // B * nW
#define BGRP    32        // B
#define NW      64        // windows per batch
#define NWIN    49        // window tokens
#define PLEN    20        // prompt tokens
#define NTOK    69        // PLEN + NWIN
#define CDIM    128
#define NH      4
#define HD      32
#define SCALE_F 0.17677669529663687f   // 32^-0.5

#define WIN_ROWS (B_TOT * NWIN)            // 100352
#define PROMPT_ROWS (BGRP * PLEN)          // 640
#define TOT_ROWS (WIN_ROWS + PROMPT_ROWS)  // 100992

// ---------------- QKV GEMM: rows -> q/k/v buffers, prompt rows deduped ----------------
__global__ __launch_bounds__(384) void qkv_kernel(
    const float* __restrict__ x, const float* __restrict__ prompts,
    const float* __restrict__ Wqkv, const float* __restrict__ bqkv,
    float* __restrict__ q_win, float* __restrict__ k_win, float* __restrict__ v_win,
    float* __restrict__ q_p, float* __restrict__ k_p, float* __restrict__ v_p)
{
    __shared__ float xs[8][128];
    const int row0 = blockIdx.x * 8;
    const int tid = threadIdx.x;

    // stage 8 rows (8*128 floats = 256 float4)
    if (tid < 256) {
        int r = tid >> 5, c4 = tid & 31;
        int row = row0 + r;
        const float4* src;
        if (row < WIN_ROWS) src = (const float4*)(x + (size_t)row * CDIM) + c4;
        else                src = (const float4*)(prompts + (size_t)(row - WIN_ROWS) * CDIM) + c4;
        *(float4*)&xs[r][c4 * 4] = *src;
    }
    __syncthreads();

    const int col = tid;  // 0..383
    float acc[8];
#pragma unroll
    for (int r = 0; r < 8; r++) acc[r] = 0.f;

    for (int k = 0; k < 128; k++) {
        float w = Wqkv[k * 384 + col];
#pragma unroll
        for (int r = 0; r < 8; r++) acc[r] += xs[r][k] * w;
    }

    const float bias = bqkv[col];
    const int which = col >> 7;       // 0=q 1=k 2=v
    const int h = (col & 127) >> 5;   // head
    const int d = col & 31;
    float* dst_win = (which == 0) ? q_win : (which == 1) ? k_win : v_win;
    float* dst_p   = (which == 0) ? q_p   : (which == 1) ? k_p   : v_p;

#pragma unroll
    for (int r = 0; r < 8; r++) {
        int row = row0 + r;
        float val = acc[r] + bias;
        if (row < WIN_ROWS) {
            int b = row / NWIN, n = row % NWIN;
            dst_win[((((size_t)b * NH + h) * NWIN) + n) * HD + d] = val;
        } else {
            int i = row - WIN_ROWS;
            int bb = i / PLEN, p = i % PLEN;
            dst_p[((((size_t)bb * NH + h) * PLEN) + p) * HD + d] = val;
        }
    }
}

// ---------------- fused attention per (window, head) ----------------
__global__ __launch_bounds__(256) void attn_kernel(
    const float* __restrict__ q_win, const float* __restrict__ k_win, const float* __restrict__ v_win,
    const float* __restrict__ q_p, const float* __restrict__ k_p, const float* __restrict__ v_p,
    const float* __restrict__ relb, const float* __restrict__ mask,
    float* __restrict__ attn_out, float* __restrict__ ori_w)
{
    __shared__ float qs[NTOK][HD];
    __shared__ float kst[HD][NTOK];   // K transposed: conflict-free QK^T inner loop
    __shared__ float vs[NTOK][HD];
    __shared__ float S[NTOK][NTOK + 1];

    const int b = blockIdx.x >> 2;
    const int h = blockIdx.x & 3;
    const int bb = b >> 6;   // batch group
    const int w = b & 63;    // window index
    const int tid = threadIdx.x;

    // stage q/k/v: 69 rows x 8 float4 each
    for (int idx = tid; idx < NTOK * 8; idx += 256) {
        int n = idx >> 3, c4 = idx & 7;
        size_t o;
        const float *qb, *kb, *vb;
        if (n < PLEN) {
            o = (((size_t)bb * NH + h) * PLEN + n) * HD + c4 * 4;
            qb = q_p; kb = k_p; vb = v_p;
        } else {
            o = (((size_t)b * NH + h) * NWIN + (n - PLEN)) * HD + c4 * 4;
            qb = q_win; kb = k_win; vb = v_win;
        }
        float4 qv = *(const float4*)(qb + o);
        float4 kv = *(const float4*)(kb + o);
        float4 vv = *(const float4*)(vb + o);
        int d0 = c4 * 4;
        *(float4*)&qs[n][d0] = qv;
        *(float4*)&vs[n][d0] = vv;
        kst[d0][n] = kv.x; kst[d0 + 1][n] = kv.y; kst[d0 + 2][n] = kv.z; kst[d0 + 3][n] = kv.w;
    }
    __syncthreads();

    // raw scores S = q @ k^T
    for (int idx = tid; idx < NTOK * NTOK; idx += 256) {
        int i = idx / NTOK, j = idx - i * NTOK;
        float acc = 0.f;
#pragma unroll
        for (int d = 0; d < HD; d++) acc += qs[i][d] * kst[d][j];
        S[i][j] = acc;
    }
    __syncthreads();

    // ori_attn_weight: raw scores, prompt queries x window keys
    for (int idx = tid; idx < PLEN * NWIN; idx += 256) {
        int i = idx / NWIN, j = idx - i * NWIN;
        ori_w[(((size_t)b * NH + h) * PLEN + i) * NWIN + j] = S[i][j + PLEN];
    }
    __syncthreads();

    // scale + rel-pos bias + mask (window-window block only)
    for (int idx = tid; idx < NTOK * NTOK; idx += 256) {
        int i = idx / NTOK, j = idx - i * NTOK;
        float v = S[i][j] * SCALE_F;
        if (i >= PLEN && j >= PLEN) {
            int ii = i - PLEN, jj = j - PLEN;
            int ih = ii / 7, iw = ii % 7, jh = jj / 7, jw = jj % 7;
            int ridx = (ih - jh + 6) * 13 + (iw - jw + 6);
            v += relb[ridx * NH + h] + mask[((size_t)w * NWIN + ii) * NWIN + jj];
        }
        S[i][j] = v;
    }
    __syncthreads();

    // row softmax: 4 lanes per row, shfl reduce (aligned 4-lane groups within wave)
    {
        const int p = tid & 3;
        for (int r = tid >> 2; r < NTOK; r += 64) {
            float m = -1e30f;
            for (int j = p; j < NTOK; j += 4) m = fmaxf(m, S[r][j]);
            m = fmaxf(m, __shfl_xor(m, 1));
            m = fmaxf(m, __shfl_xor(m, 2));
            float s = 0.f;
            for (int j = p; j < NTOK; j += 4) { float e = __expf(S[r][j] - m); S[r][j] = e; s += e; }
            s += __shfl_xor(s, 1);
            s += __shfl_xor(s, 2);
            float inv = 1.f / s;
            for (int j = p; j < NTOK; j += 4) S[r][j] *= inv;
        }
    }
    __syncthreads();

    // O = P @ V  -> (b, n, h*32+d) layout (== transpose(0,2,1,3).reshape)
    for (int idx = tid; idx < NTOK * HD; idx += 256) {
        int n = idx >> 5, d = idx & 31;
        float acc = 0.f;
        for (int m2 = 0; m2 < NTOK; m2++) acc += S[n][m2] * vs[m2][d];
        attn_out[((size_t)b * NTOK + n) * CDIM + h * HD + d] = acc;
    }
}

// ---------------- output projection ----------------
__global__ __launch_bounds__(128) void proj_kernel(
    const float* __restrict__ attn_out, const float* __restrict__ Wp, const float* __restrict__ bp,
    float* __restrict__ x_out, float* __restrict__ promptproj)
{
    __shared__ float xs[8][128];
    const int row0 = blockIdx.x * 8;
    const int tid = threadIdx.x;

    // 8*128 floats = 256 float4, 128 threads -> 2 iters
    for (int idx = tid; idx < 256; idx += 128) {
        int r = idx >> 5, c4 = idx & 31;
        *(float4*)&xs[r][c4 * 4] =
            *((const float4*)(attn_out + (size_t)(row0 + r) * CDIM) + c4);
    }
    __syncthreads();

    const int col = tid;
    float acc[8];
#pragma unroll
    for (int r = 0; r < 8; r++) acc[r] = 0.f;

    for (int k = 0; k < 128; k++) {
        float wv = Wp[k * 128 + col];
#pragma unroll
        for (int r = 0; r < 8; r++) acc[r] += xs[r][k] * wv;
    }

    const float bias = bp[col];
#pragma unroll
    for (int r = 0; r < 8; r++) {
        int row = row0 + r;
        int b = row / NTOK, n = row % NTOK;
        float val = acc[r] + bias;
        if (n >= PLEN) x_out[((size_t)b * NWIN + (n - PLEN)) * CDIM + col] = val;
        else           promptproj[((size_t)b * PLEN + n) * CDIM + col] = val;
    }
}

// ---------------- prompt mean over 64 windows ----------------
__global__ __launch_bounds__(256) void mean_kernel(
    const float* __restrict__ promptproj, float* __restrict__ prompts_out)
{
    int idx = blockIdx.x * 256 + threadIdx.x;
    if (idx >= BGRP * PLEN * CDIM) return;
    int c = idx & 127;
    int p = (idx >> 7) % PLEN;
    int bb = idx / (PLEN * CDIM);
    size_t base = (((size_t)bb * NW) * PLEN + p) * CDIM + c;
    float s = 0.f;
    for (int w = 0; w < NW; w++) s += promptproj[base + (size_t)w * (PLEN * CDIM)];
    prompts_out[idx] = s * (1.f / 64.f);
}

extern "C" void kernel_launch(void* const* d_in, const int* in_sizes, int n_in,
                              void* d_out, int out_size, void* d_ws, size_t ws_size,
                              hipStream_t stream)
{
    const float* x       = (const float*)d_in[0];
    const float* prompts = (const float*)d_in[1];
    const float* mask    = (const float*)d_in[2];
    const float* relb    = (const float*)d_in[3];
    const float* Wqkv    = (const float*)d_in[4];
    const float* bqkv    = (const float*)d_in[5];
    const float* Wproj   = (const float*)d_in[6];
    const float* bproj   = (const float*)d_in[7];

    float* out = (float*)d_out;
    float* x_out       = out;                                   // 2048*49*128
    float* ori_w       = out + (size_t)B_TOT * NWIN * CDIM;     // 2048*4*20*49
    float* prompts_out = ori_w + (size_t)B_TOT * NH * PLEN * NWIN;

    float* ws = (float*)d_ws;
    size_t off = 0;
    const size_t winQKV = (size_t)B_TOT * NH * NWIN * HD;   // 12,845,056
    const size_t pQKV   = (size_t)BGRP * NH * PLEN * HD;    // 81,920
    float* q_win = ws + off; off += winQKV;
    float* k_win = ws + off; off += winQKV;
    float* v_win = ws + off; off += winQKV;
    float* q_p   = ws + off; off += pQKV;
    float* k_p   = ws + off; off += pQKV;
    float* v_p   = ws + off; off += pQKV;
    float* attn_out   = ws + off; off += (size_t)B_TOT * NTOK * CDIM;  // 18,087,936
    float* promptproj = ws + off; off += (size_t)B_TOT * PLEN * CDIM;  // 5,242,880

    qkv_kernel<<<TOT_ROWS / 8, 384, 0, stream>>>(x, prompts, Wqkv, bqkv,
                                                 q_win, k_win, v_win, q_p, k_p, v_p);
    attn_kernel<<<B_TOT * NH, 256, 0, stream>>>(q_win, k_win, v_win, q_p, k_p, v_p,
                                                relb, mask, attn_out, ori_w);
    proj_kernel<<<(B_TOT * NTOK) / 8, 128, 0, stream>>>(attn_out, Wproj, bproj,
                                                        x_out, promptproj);
    mean_kernel<<<(BGRP * PLEN * CDIM + 255) / 256, 256, 0, stream>>>(promptproj, prompts_out);
}

// Round 3
// 527.201 us; speedup vs baseline: 1.3885x; 1.3885x over previous
//
#include <hip/hip_runtime.h>
#include <hip/hip_bf16.h>

#define B_TOT   2048      // B * nW
#define BGRP    32        // B
#define NW      64        // windows per batch
#define NWIN    49        // window tokens
#define PLEN    20        // prompt tokens
#define NTOK    69        // PLEN + NWIN
#define CDIM    128
#define NH      4
#define HD      32
#define SCALE_F 0.17677669529663687f   // 32^-0.5

#define WIN_ROWS (B_TOT * NWIN)            // 100352
#define PROMPT_ROWS (BGRP * PLEN)          // 640
#define TOT_ROWS (WIN_ROWS + PROMPT_ROWS)  // 100992  = 64*1578
#define PROJ_ROWS (B_TOT * NTOK)           // 141312  = 64*2208

__device__ __forceinline__ float4 f4fma(float4 a, float s, float4 v) {
    a.x = fmaf(s, v.x, a.x);
    a.y = fmaf(s, v.y, a.y);
    a.z = fmaf(s, v.z, a.z);
    a.w = fmaf(s, v.w, a.w);
    return a;
}

// ---------------- QKV GEMM: 64x64 tile, BK=32, 256 thr, 4x4 register tile ----------------
__global__ __launch_bounds__(256) void qkv_kernel(
    const float* __restrict__ x, const float* __restrict__ prompts,
    const float* __restrict__ Wqkv, const float* __restrict__ bqkv,
    float* __restrict__ q_win, float* __restrict__ k_win, float* __restrict__ v_win,
    float* __restrict__ q_p, float* __restrict__ k_p, float* __restrict__ v_p)
{
    __shared__ __align__(16) float xs[32][68];   // [k][row], padded
    __shared__ __align__(16) float ws[32][64];   // [k][col]
    const int m0 = blockIdx.x * 64;
    const int n0 = blockIdx.y * 64;
    const int tid = threadIdx.x;
    const int mt = tid >> 4;   // 0..15
    const int nt = tid & 15;   // 0..15

    float4 acc[4];
    acc[0] = acc[1] = acc[2] = acc[3] = make_float4(0.f, 0.f, 0.f, 0.f);

    for (int k0 = 0; k0 < 128; k0 += 32) {
#pragma unroll
        for (int it = 0; it < 2; it++) {
            int idx = tid + it * 256;
            // x tile (transpose on store)
            int r = idx >> 3, c = idx & 7;
            int row = m0 + r;
            const float* src = (row < WIN_ROWS) ? x + (size_t)row * CDIM
                                                : prompts + (size_t)(row - WIN_ROWS) * CDIM;
            float4 xv = *(const float4*)(src + k0 + c * 4);
            xs[c * 4 + 0][r] = xv.x; xs[c * 4 + 1][r] = xv.y;
            xs[c * 4 + 2][r] = xv.z; xs[c * 4 + 3][r] = xv.w;
            // W tile
            int kk = idx >> 4, n4 = idx & 15;
            *(float4*)&ws[kk][n4 * 4] =
                *(const float4*)(Wqkv + (size_t)(k0 + kk) * 384 + n0 + n4 * 4);
        }
        __syncthreads();
#pragma unroll
        for (int kk = 0; kk < 32; kk++) {
            float4 xv = *(const float4*)&xs[kk][mt * 4];
            float4 wv = *(const float4*)&ws[kk][nt * 4];
            acc[0] = f4fma(acc[0], xv.x, wv);
            acc[1] = f4fma(acc[1], xv.y, wv);
            acc[2] = f4fma(acc[2], xv.z, wv);
            acc[3] = f4fma(acc[3], xv.w, wv);
        }
        __syncthreads();
    }

    const int c0 = n0 + nt * 4;
    const int which = c0 >> 7;
    const int h = (c0 & 127) >> 5;
    const int d0 = c0 & 31;
    float4 bias = *(const float4*)(bqkv + c0);
    float* dstw = (which == 0) ? q_win : (which == 1) ? k_win : v_win;
    float* dstp = (which == 0) ? q_p   : (which == 1) ? k_p   : v_p;

#pragma unroll
    for (int r = 0; r < 4; r++) {
        int row = m0 + mt * 4 + r;
        float4 val = make_float4(acc[r].x + bias.x, acc[r].y + bias.y,
                                 acc[r].z + bias.z, acc[r].w + bias.w);
        if (row < WIN_ROWS) {
            int b = row / NWIN, n = row % NWIN;
            *(float4*)&dstw[((((size_t)b * NH + h) * NWIN) + n) * HD + d0] = val;
        } else {
            int i = row - WIN_ROWS;
            int bb = i / PLEN, p = i % PLEN;
            *(float4*)&dstp[((((size_t)bb * NH + h) * PLEN) + p) * HD + d0] = val;
        }
    }
}

// ---------------- fused attention per (window, head), register-tiled ----------------
__global__ __launch_bounds__(256) void attn_kernel(
    const float* __restrict__ q_win, const float* __restrict__ k_win, const float* __restrict__ v_win,
    const float* __restrict__ q_p, const float* __restrict__ k_p, const float* __restrict__ v_p,
    const float* __restrict__ relb, const float* __restrict__ mask,
    float* __restrict__ attn_out, float* __restrict__ ori_w)
{
    __shared__ __align__(16) float qs[NTOK][36];   // row stride 36 floats (16B-aligned, bank-spread)
    __shared__ __align__(16) float kst[HD][72];    // K transposed, cols 69..71 zero
    __shared__ __align__(16) float vs[72][HD];     // rows 69..71 zero
    __shared__ __align__(16) float S[NTOK][72];    // cols 69..71 become 0 from zero-padded kst

    const int b = blockIdx.x >> 2;
    const int h = blockIdx.x & 3;
    const int bb = b >> 6;   // batch group
    const int w = b & 63;    // window index
    const int tid = threadIdx.x;

    float4* const S4   = (float4*)S;     // row stride 18
    float4* const qs4  = (float4*)qs;    // row stride 9
    float4* const kst4 = (float4*)kst;   // row stride 18
    float4* const vs4  = (float4*)vs;    // row stride 8

    // stage q/k/v
    for (int idx = tid; idx < NTOK * 8; idx += 256) {
        int n = idx >> 3, c4 = idx & 7;
        size_t o;
        const float *qb, *kb, *vb;
        if (n < PLEN) {
            o = (((size_t)bb * NH + h) * PLEN + n) * HD + c4 * 4;
            qb = q_p; kb = k_p; vb = v_p;
        } else {
            o = (((size_t)b * NH + h) * NWIN + (n - PLEN)) * HD + c4 * 4;
            qb = q_win; kb = k_win; vb = v_win;
        }
        float4 qv = *(const float4*)(qb + o);
        float4 kv = *(const float4*)(kb + o);
        float4 vv = *(const float4*)(vb + o);
        qs4[n * 9 + c4] = qv;
        vs4[n * 8 + c4] = vv;
        int d0 = c4 * 4;
        kst[d0][n] = kv.x; kst[d0 + 1][n] = kv.y; kst[d0 + 2][n] = kv.z; kst[d0 + 3][n] = kv.w;
    }
    // zero pads
    if (tid < 96) {                      // kst cols 69..71
        int d = tid >> 2, j = 69 + (tid & 3);
        if ((tid & 3) < 3) kst[d][j] = 0.f;
    }
    if (tid >= 128 && tid < 224) {       // vs rows 69..71
        int i = tid - 128;
        vs[69 + (i >> 5)][i & 31] = 0.f;
    }
    __syncthreads();

    // ---- QK^T: items = 23 i-tiles(x3) * 18 j-tiles(x4) ----
    for (int item = tid; item < 23 * 18; item += 256) {
        int it = item / 18, jt = item % 18;
        int i0 = it * 3;
        float4 a0 = make_float4(0.f, 0.f, 0.f, 0.f), a1 = a0, a2 = a0;
#pragma unroll
        for (int dc = 0; dc < 8; dc++) {
            float4 qa = qs4[i0 * 9 + dc];
            float4 qb2 = qs4[(i0 + 1) * 9 + dc];
            float4 qc = qs4[(i0 + 2) * 9 + dc];
            float4 k0 = kst4[(dc * 4 + 0) * 18 + jt];
            float4 k1 = kst4[(dc * 4 + 1) * 18 + jt];
            float4 k2 = kst4[(dc * 4 + 2) * 18 + jt];
            float4 k3 = kst4[(dc * 4 + 3) * 18 + jt];
            a0 = f4fma(a0, qa.x, k0); a0 = f4fma(a0, qa.y, k1);
            a0 = f4fma(a0, qa.z, k2); a0 = f4fma(a0, qa.w, k3);
            a1 = f4fma(a1, qb2.x, k0); a1 = f4fma(a1, qb2.y, k1);
            a1 = f4fma(a1, qb2.z, k2); a1 = f4fma(a1, qb2.w, k3);
            a2 = f4fma(a2, qc.x, k0); a2 = f4fma(a2, qc.y, k1);
            a2 = f4fma(a2, qc.z, k2); a2 = f4fma(a2, qc.w, k3);
        }
        S4[i0 * 18 + jt] = a0;
        S4[(i0 + 1) * 18 + jt] = a1;
        S4[(i0 + 2) * 18 + jt] = a2;
    }
    __syncthreads();

    // ori_attn_weight: raw scores, prompt queries x window keys
    for (int idx = tid; idx < PLEN * NWIN; idx += 256) {
        int i = idx / NWIN, j = idx - i * NWIN;
        ori_w[(((size_t)b * NH + h) * PLEN + i) * NWIN + j] = S[i][j + PLEN];
    }
    __syncthreads();

    // scale + rel-pos bias + mask
    for (int idx = tid; idx < NTOK * NTOK; idx += 256) {
        int i = idx / NTOK, j = idx - i * NTOK;
        float v = S[i][j] * SCALE_F;
        if (i >= PLEN && j >= PLEN) {
            int ii = i - PLEN, jj = j - PLEN;
            int ih = ii / 7, iw = ii % 7, jh = jj / 7, jw = jj % 7;
            int ridx = (ih - jh + 6) * 13 + (iw - jw + 6);
            v += relb[ridx * NH + h] + mask[((size_t)w * NWIN + ii) * NWIN + jj];
        }
        S[i][j] = v;
    }
    __syncthreads();

    // row softmax: 4 lanes per row
    {
        const int p = tid & 3;
        for (int r = tid >> 2; r < NTOK; r += 64) {
            float m = -1e30f;
            for (int j = p; j < NTOK; j += 4) m = fmaxf(m, S[r][j]);
            m = fmaxf(m, __shfl_xor(m, 1));
            m = fmaxf(m, __shfl_xor(m, 2));
            float s = 0.f;
            for (int j = p; j < NTOK; j += 4) { float e = __expf(S[r][j] - m); S[r][j] = e; s += e; }
            s += __shfl_xor(s, 1);
            s += __shfl_xor(s, 2);
            float inv = 1.f / s;
            for (int j = p; j < NTOK; j += 4) S[r][j] *= inv;
        }
    }
    __syncthreads();

    // ---- O = P @ V: items = 23 n-tiles(x3) * 8 d-tiles(x4); S cols 69..71 are 0 ----
    for (int item = tid; item < 23 * 8; item += 256) {
        int nt = item >> 3, d4 = item & 7;
        int n0 = nt * 3, d0 = d4 * 4;
        float4 a0 = make_float4(0.f, 0.f, 0.f, 0.f), a1 = a0, a2 = a0;
#pragma unroll 6
        for (int mc = 0; mc < 18; mc++) {
            float4 s0 = S4[n0 * 18 + mc];
            float4 s1 = S4[(n0 + 1) * 18 + mc];
            float4 s2 = S4[(n0 + 2) * 18 + mc];
            float4 v0 = vs4[(mc * 4 + 0) * 8 + d4];
            float4 v1 = vs4[(mc * 4 + 1) * 8 + d4];
            float4 v2 = vs4[(mc * 4 + 2) * 8 + d4];
            float4 v3 = vs4[(mc * 4 + 3) * 8 + d4];
            a0 = f4fma(a0, s0.x, v0); a0 = f4fma(a0, s0.y, v1);
            a0 = f4fma(a0, s0.z, v2); a0 = f4fma(a0, s0.w, v3);
            a1 = f4fma(a1, s1.x, v0); a1 = f4fma(a1, s1.y, v1);
            a1 = f4fma(a1, s1.z, v2); a1 = f4fma(a1, s1.w, v3);
            a2 = f4fma(a2, s2.x, v0); a2 = f4fma(a2, s2.y, v1);
            a2 = f4fma(a2, s2.z, v2); a2 = f4fma(a2, s2.w, v3);
        }
        size_t base = ((size_t)b * NTOK + n0) * CDIM + h * HD + d0;
        *(float4*)&attn_out[base] = a0;
        *(float4*)&attn_out[base + CDIM] = a1;
        *(float4*)&attn_out[base + 2 * CDIM] = a2;
    }
}

// ---------------- output projection: 64x64 tile GEMM ----------------
__global__ __launch_bounds__(256) void proj_kernel(
    const float* __restrict__ attn_out, const float* __restrict__ Wp, const float* __restrict__ bp,
    float* __restrict__ x_out, float* __restrict__ promptproj)
{
    __shared__ __align__(16) float xs[32][68];
    __shared__ __align__(16) float ws[32][64];
    const int m0 = blockIdx.x * 64;
    const int n0 = blockIdx.y * 64;
    const int tid = threadIdx.x;
    const int mt = tid >> 4;
    const int nt = tid & 15;

    float4 acc[4];
    acc[0] = acc[1] = acc[2] = acc[3] = make_float4(0.f, 0.f, 0.f, 0.f);

    for (int k0 = 0; k0 < 128; k0 += 32) {
#pragma unroll
        for (int it = 0; it < 2; it++) {
            int idx = tid + it * 256;
            int r = idx >> 3, c = idx & 7;
            float4 xv = *(const float4*)(attn_out + (size_t)(m0 + r) * CDIM + k0 + c * 4);
            xs[c * 4 + 0][r] = xv.x; xs[c * 4 + 1][r] = xv.y;
            xs[c * 4 + 2][r] = xv.z; xs[c * 4 + 3][r] = xv.w;
            int kk = idx >> 4, n4 = idx & 15;
            *(float4*)&ws[kk][n4 * 4] =
                *(const float4*)(Wp + (size_t)(k0 + kk) * CDIM + n0 + n4 * 4);
        }
        __syncthreads();
#pragma unroll
        for (int kk = 0; kk < 32; kk++) {
            float4 xv = *(const float4*)&xs[kk][mt * 4];
            float4 wv = *(const float4*)&ws[kk][nt * 4];
            acc[0] = f4fma(acc[0], xv.x, wv);
            acc[1] = f4fma(acc[1], xv.y, wv);
            acc[2] = f4fma(acc[2], xv.z, wv);
            acc[3] = f4fma(acc[3], xv.w, wv);
        }
        __syncthreads();
    }

    const int c0 = n0 + nt * 4;
    float4 bias = *(const float4*)(bp + c0);
#pragma unroll
    for (int r = 0; r < 4; r++) {
        int row = m0 + mt * 4 + r;
        int bidx = row / NTOK, n = row % NTOK;
        float4 val = make_float4(acc[r].x + bias.x, acc[r].y + bias.y,
                                 acc[r].z + bias.z, acc[r].w + bias.w);
        if (n >= PLEN)
            *(float4*)&x_out[((size_t)bidx * NWIN + (n - PLEN)) * CDIM + c0] = val;
        else
            *(float4*)&promptproj[((size_t)bidx * PLEN + n) * CDIM + c0] = val;
    }
}

// ---------------- prompt mean over 64 windows ----------------
__global__ __launch_bounds__(256) void mean_kernel(
    const float* __restrict__ promptproj, float* __restrict__ prompts_out)
{
    int idx = blockIdx.x * 256 + threadIdx.x;
    if (idx >= BGRP * PLEN * CDIM) return;
    int c = idx & 127;
    int p = (idx >> 7) % PLEN;
    int bb = idx / (PLEN * CDIM);
    size_t base = (((size_t)bb * NW) * PLEN + p) * CDIM + c;
    float s = 0.f;
    for (int w = 0; w < NW; w++) s += promptproj[base + (size_t)w * (PLEN * CDIM)];
    prompts_out[idx] = s * (1.f / 64.f);
}

extern "C" void kernel_launch(void* const* d_in, const int* in_sizes, int n_in,
                              void* d_out, int out_size, void* d_ws, size_t ws_size,
                              hipStream_t stream)
{
    const float* x       = (const float*)d_in[0];
    const float* prompts = (const float*)d_in[1];
    const float* mask    = (const float*)d_in[2];
    const float* relb    = (const float*)d_in[3];
    const float* Wqkv    = (const float*)d_in[4];
    const float* bqkv    = (const float*)d_in[5];
    const float* Wproj   = (const float*)d_in[6];
    const float* bproj   = (const float*)d_in[7];

    float* out = (float*)d_out;
    float* x_out       = out;                                   // 2048*49*128
    float* ori_w       = out + (size_t)B_TOT * NWIN * CDIM;     // 2048*4*20*49
    float* prompts_out = ori_w + (size_t)B_TOT * NH * PLEN * NWIN;

    float* ws = (float*)d_ws;
    size_t off = 0;
    const size_t winQKV = (size_t)B_TOT * NH * NWIN * HD;
    const size_t pQKV   = (size_t)BGRP * NH * PLEN * HD;
    float* q_win = ws + off; off += winQKV;
    float* k_win = ws + off; off += winQKV;
    float* v_win = ws + off; off += winQKV;
    float* q_p   = ws + off; off += pQKV;
    float* k_p   = ws + off; off += pQKV;
    float* v_p   = ws + off; off += pQKV;
    float* attn_out   = ws + off; off += (size_t)B_TOT * NTOK * CDIM;
    float* promptproj = ws + off; off += (size_t)B_TOT * PLEN * CDIM;

    qkv_kernel<<<dim3(TOT_ROWS / 64, 6), 256, 0, stream>>>(x, prompts, Wqkv, bqkv,
                                                           q_win, k_win, v_win, q_p, k_p, v_p);
    attn_kernel<<<B_TOT * NH, 256, 0, stream>>>(q_win, k_win, v_win, q_p, k_p, v_p,
                                                relb, mask, attn_out, ori_w);
    proj_kernel<<<dim3(PROJ_ROWS / 64, 2), 256, 0, stream>>>(attn_out, Wproj, bproj,
                                                             x_out, promptproj);
    mean_kernel<<<(BGRP * PLEN * CDIM + 255) / 256, 256, 0, stream>>>(promptproj, prompts_out);
}

// Round 4
// 306.175 us; speedup vs baseline: 2.3909x; 1.7219x over previous
//
#include <hip/hip_runtime.h>
#include <hip/hip_bf16.h>

#define B_TOT   2048
#define BGRP    32
#define NW      64
#define NWIN    49
#define PLEN    20
#define NTOK    69
#define CDIM    128
#define NH      4
#define HD      32
#define SCALE_F 0.17677669529663687f

#define WIN_ROWS (B_TOT * NWIN)            // 100352 = 784*128
#define PROMPT_ROWS (BGRP * PLEN)          // 640
#define TOT_ROWS (WIN_ROWS + PROMPT_ROWS)  // 100992 = 789*128
#define PROJ_ROWS (B_TOT * NTOK)           // 141312 = 1104*128

typedef unsigned short ushort_t;
typedef __attribute__((ext_vector_type(8))) short bf16x8;
typedef __attribute__((ext_vector_type(4))) float f32x4;

__device__ __forceinline__ ushort_t f2b(float f) {
    union { float f; unsigned u; } v; v.f = f;
    unsigned r = v.u + 0x7FFFu + ((v.u >> 16) & 1u);
    return (ushort_t)(r >> 16);
}

// ---------- prep: transpose+convert weights to bf16 ----------
__global__ __launch_bounds__(256) void convw_kernel(
    const float* __restrict__ Wqkv, const float* __restrict__ Wproj,
    ushort_t* __restrict__ Wtq, ushort_t* __restrict__ Wtp)
{
    int idx = blockIdx.x * 256 + threadIdx.x;   // < 65536
    if (idx < 384 * 128) {
        int n = idx >> 7, k = idx & 127;
        Wtq[idx] = f2b(Wqkv[k * 384 + n]);
    } else {
        int i = idx - 384 * 128;
        int n = i >> 7, k = i & 127;
        Wtp[i] = f2b(Wproj[k * 128 + n]);
    }
}

// ---------- prep: fused rel-bias + mask table bm[(w*4+h)][ii][jj] ----------
__global__ __launch_bounds__(256) void bm_kernel(
    const float* __restrict__ relb, const float* __restrict__ mask, float* __restrict__ bm)
{
    int idx = blockIdx.x * 256 + threadIdx.x;   // < 64*4*49*49 = 614656
    int jj = idx % 49; int t = idx / 49; int ii = t % 49; int wh = t / 49;
    int h = wh & 3, w = wh >> 2;
    int ridx = (ii / 7 - jj / 7 + 6) * 13 + (ii % 7 - jj % 7 + 6);
    bm[idx] = relb[ridx * NH + h] + mask[((size_t)w * 49 + ii) * 49 + jj];
}

// ---------- QKV: 128x128 MFMA GEMM tile, N=384 in 3 y-blocks ----------
__global__ __launch_bounds__(256) void qkv_kernel(
    const float* __restrict__ x, const float* __restrict__ prompts,
    const ushort_t* __restrict__ Wtq, const float* __restrict__ bqkv,
    ushort_t* __restrict__ q_win, ushort_t* __restrict__ k_win, ushort_t* __restrict__ v_win,
    ushort_t* __restrict__ q_p, ushort_t* __restrict__ k_p, ushort_t* __restrict__ v_p)
{
    __shared__ __align__(16) ushort_t As[128][136];
    __shared__ __align__(16) ushort_t Bs[128][136];
    const int m0 = blockIdx.x * 128;
    const int by = blockIdx.y;
    const int tid = threadIdx.x;

    for (int it = tid; it < 128 * 16; it += 256) {
        int r = it >> 4, ch = it & 15;
        int row = m0 + r;
        const float* src = (row < WIN_ROWS) ? x + (size_t)row * CDIM + ch * 8
                                            : prompts + (size_t)(row - WIN_ROWS) * CDIM + ch * 8;
        float4 v0 = *(const float4*)src;
        float4 v1 = *(const float4*)(src + 4);
        ushort_t tmp[8] = {f2b(v0.x), f2b(v0.y), f2b(v0.z), f2b(v0.w),
                           f2b(v1.x), f2b(v1.y), f2b(v1.z), f2b(v1.w)};
        *(uint4*)&As[r][ch * 8] = *(uint4*)tmp;
    }
    for (int it = tid; it < 128 * 16; it += 256) {
        int r = it >> 4, ch = it & 15;
        *(uint4*)&Bs[r][ch * 8] = *(const uint4*)(Wtq + ((size_t)(by * 128 + r)) * 128 + ch * 8);
    }
    __syncthreads();

    const int lane = tid & 63, wv = tid >> 6;
    const int wr = wv >> 1, wc = wv & 1;
    const int c = lane & 15, quad = lane >> 4;

    f32x4 acc[4][4];
#pragma unroll
    for (int i = 0; i < 4; i++)
#pragma unroll
        for (int j = 0; j < 4; j++) acc[i][j] = (f32x4){0.f, 0.f, 0.f, 0.f};

#pragma unroll
    for (int kc = 0; kc < 4; kc++) {
        bf16x8 a[4], b[4];
#pragma unroll
        for (int i = 0; i < 4; i++) a[i] = *(const bf16x8*)&As[wr * 64 + i * 16 + c][kc * 32 + quad * 8];
#pragma unroll
        for (int j = 0; j < 4; j++) b[j] = *(const bf16x8*)&Bs[wc * 64 + j * 16 + c][kc * 32 + quad * 8];
#pragma unroll
        for (int i = 0; i < 4; i++)
#pragma unroll
            for (int j = 0; j < 4; j++)
                acc[i][j] = __builtin_amdgcn_mfma_f32_16x16x32_bf16(a[i], b[j], acc[i][j], 0, 0, 0);
    }

    ushort_t* dw = (by == 0) ? q_win : (by == 1) ? k_win : v_win;
    ushort_t* dp = (by == 0) ? q_p   : (by == 1) ? k_p   : v_p;
    const bool iswin = (m0 < WIN_ROWS);   // boundary 100352 = 784*128: blocks never straddle

#pragma unroll
    for (int j = 0; j < 4; j++) {
        int col = wc * 64 + j * 16 + c;
        float bias = bqkv[by * 128 + col];
        int h = col >> 5, d = col & 31;
#pragma unroll
        for (int i = 0; i < 4; i++) {
            int row0 = m0 + wr * 64 + i * 16 + quad * 4;
            if (iswin) {
                int bidx = row0 / 49, n = row0 - bidx * 49;
#pragma unroll
                for (int rr = 0; rr < 4; rr++) {
                    dw[(((size_t)bidx * NH + h) * NWIN + n) * HD + d] = f2b(acc[i][j][rr] + bias);
                    if (++n == 49) { n = 0; ++bidx; }
                }
            } else {
                int ir = row0 - WIN_ROWS;
                int bb2 = ir / 20, p = ir - bb2 * 20;
#pragma unroll
                for (int rr = 0; rr < 4; rr++) {
                    dp[(((size_t)bb2 * NH + h) * PLEN + p) * HD + d] = f2b(acc[i][j][rr] + bias);
                    if (++p == 20) { p = 0; ++bb2; }
                }
            }
        }
    }
}

// ---------- fused attention per (window, head): MFMA + in-register softmax ----------
__global__ __launch_bounds__(256) void attn_kernel(
    const ushort_t* __restrict__ q_win, const ushort_t* __restrict__ k_win, const ushort_t* __restrict__ v_win,
    const ushort_t* __restrict__ q_p, const ushort_t* __restrict__ k_p, const ushort_t* __restrict__ v_p,
    const float* __restrict__ bm,
    ushort_t* __restrict__ attn_out, float* __restrict__ ori_w)
{
    __shared__ __align__(16) ushort_t Qs[80][72];    // stride 144B: 2-way-max b128 reads
    __shared__ __align__(16) ushort_t Ks[80][72];
    __shared__ __align__(16) ushort_t Vt[32][112];   // V transposed [d][m], m-padded to 96
    __shared__ __align__(16) ushort_t Ps[80][104];   // P bf16, cols padded to 96

    const int b = blockIdx.x >> 2;
    const int h = blockIdx.x & 3;
    const int bb = b >> 6;
    const int w = b & 63;
    const int tid = threadIdx.x;

    // ---- stage Q,K (rows 0..68), V transposed ----
    for (int it = tid; it < 69 * 4; it += 256) {
        int n = it >> 2, ch = it & 3;
        size_t o;
        const ushort_t *qb, *kb, *vb;
        if (n < PLEN) {
            o = (((size_t)bb * NH + h) * PLEN + n) * HD + ch * 8;
            qb = q_p; kb = k_p; vb = v_p;
        } else {
            o = (((size_t)b * NH + h) * NWIN + (n - PLEN)) * HD + ch * 8;
            qb = q_win; kb = k_win; vb = v_win;
        }
        *(uint4*)&Qs[n][ch * 8] = *(const uint4*)(qb + o);
        *(uint4*)&Ks[n][ch * 8] = *(const uint4*)(kb + o);
        uint4 vv = *(const uint4*)(vb + o);
        ushort_t tmp[8]; *(uint4*)tmp = vv;
#pragma unroll
        for (int d = 0; d < 8; d++) Vt[ch * 8 + d][n] = tmp[d];
    }
    // zero pads: Q/K rows 69..79
    for (int it = tid; it < 11 * 9 * 2; it += 256) {
        int which = it / 99, rem = it % 99;
        int r = 69 + rem / 9, ch = rem % 9;
        uint4 z = {0u, 0u, 0u, 0u};
        if (which == 0) *(uint4*)&Qs[r][ch * 8] = z;
        else            *(uint4*)&Ks[r][ch * 8] = z;
    }
    // zero Vt cols 69..95 (NaN-safety against stale LDS)
    for (int it = tid; it < 32 * 27; it += 256) Vt[it / 27][69 + it % 27] = 0;
    // zero Ps cols 80..95
    for (int it = tid; it < 80 * 2; it += 256) {
        uint4 z = {0u, 0u, 0u, 0u};
        *(uint4*)&Ps[it >> 1][80 + (it & 1) * 8] = z;
    }
    __syncthreads();

    const int lane = tid & 63, wv = tid >> 6;
    const int c = lane & 15, quad = lane >> 4;
    const float* bmw = bm + (size_t)(w * NH + h) * (49 * 49);
    float* OtF = (float*)&Qs[0][0];   // reuse Qs as f32 O, stride 36 floats (rows owned per-wave)

    for (int itile = wv; itile < 5; itile += 4) {
        bf16x8 aq = *(const bf16x8*)&Qs[itile * 16 + c][quad * 8];
        f32x4 s[5];
#pragma unroll
        for (int j = 0; j < 5; j++) {
            bf16x8 bk = *(const bf16x8*)&Ks[j * 16 + c][quad * 8];
            s[j] = __builtin_amdgcn_mfma_f32_16x16x32_bf16(aq, bk, (f32x4){0.f, 0.f, 0.f, 0.f}, 0, 0, 0);
        }
        const int mbase = itile * 16 + quad * 4;

        // raw scores -> ori_attn_weight (prompt queries x window keys)
        if (mbase < 20) {
#pragma unroll
            for (int j = 1; j < 5; j++) {
                int col = j * 16 + c;
                if (col >= 20 && col < 69) {
#pragma unroll
                    for (int rr = 0; rr < 4; rr++) {
                        int m = mbase + rr;
                        if (m < 20)
                            ori_w[(((size_t)b * NH + h) * PLEN + m) * NWIN + (col - 20)] = s[j][rr];
                    }
                }
            }
        }
        // scale + fused bias/mask; invalidate pad cols
#pragma unroll
        for (int j = 0; j < 5; j++) {
            int col = j * 16 + c;
#pragma unroll
            for (int rr = 0; rr < 4; rr++) {
                int m = mbase + rr;
                float v;
                if (col >= 69) v = -1e30f;
                else {
                    v = s[j][rr] * SCALE_F;
                    if (m >= 20 && m < 69 && col >= 20)
                        v += bmw[(m - 20) * 49 + (col - 20)];
                }
                s[j][rr] = v;
            }
        }
        // in-register softmax: row m lives on 16 lanes of this quad
#pragma unroll
        for (int rr = 0; rr < 4; rr++) {
            float mx = s[0][rr];
#pragma unroll
            for (int j = 1; j < 5; j++) mx = fmaxf(mx, s[j][rr]);
            mx = fmaxf(mx, __shfl_xor(mx, 1));
            mx = fmaxf(mx, __shfl_xor(mx, 2));
            mx = fmaxf(mx, __shfl_xor(mx, 4));
            mx = fmaxf(mx, __shfl_xor(mx, 8));
            float e[5], sum = 0.f;
#pragma unroll
            for (int j = 0; j < 5; j++) { e[j] = __expf(s[j][rr] - mx); sum += e[j]; }
            sum += __shfl_xor(sum, 1);
            sum += __shfl_xor(sum, 2);
            sum += __shfl_xor(sum, 4);
            sum += __shfl_xor(sum, 8);
            float inv = 1.f / sum;
            int m = mbase + rr;
#pragma unroll
            for (int j = 0; j < 5; j++) Ps[m][j * 16 + c] = f2b(e[j] * inv);
        }
        // PV for this n-tile (own rows only -> no barrier needed)
#pragma unroll
        for (int dt = 0; dt < 2; dt++) {
            f32x4 o = {0.f, 0.f, 0.f, 0.f};
#pragma unroll
            for (int kc = 0; kc < 3; kc++) {
                bf16x8 pa = *(const bf16x8*)&Ps[itile * 16 + c][kc * 32 + quad * 8];
                bf16x8 vb = *(const bf16x8*)&Vt[dt * 16 + c][kc * 32 + quad * 8];
                o = __builtin_amdgcn_mfma_f32_16x16x32_bf16(pa, vb, o, 0, 0, 0);
            }
#pragma unroll
            for (int rr = 0; rr < 4; rr++)
                OtF[(itile * 16 + quad * 4 + rr) * 36 + dt * 16 + c] = o[rr];
        }
    }
    __syncthreads();

    // cooperative O write: bf16, coalesced rows
    for (int it = tid; it < 69 * 8; it += 256) {
        int n = it >> 3, ch = it & 7;
        float4 ov = *(const float4*)&OtF[n * 36 + ch * 4];
        uint2 pk;
        pk.x = (unsigned)f2b(ov.x) | ((unsigned)f2b(ov.y) << 16);
        pk.y = (unsigned)f2b(ov.z) | ((unsigned)f2b(ov.w) << 16);
        *(uint2*)(attn_out + ((size_t)b * NTOK + n) * CDIM + h * HD + ch * 4) = pk;
    }
}

// ---------- proj: 128x128 MFMA GEMM, N=128 ----------
__global__ __launch_bounds__(256) void proj_kernel(
    const ushort_t* __restrict__ attn_out, const ushort_t* __restrict__ Wtp,
    const float* __restrict__ bproj,
    float* __restrict__ x_out, float* __restrict__ promptproj)
{
    __shared__ __align__(16) ushort_t As[128][136];
    __shared__ __align__(16) ushort_t Bs[128][136];
    const int m0 = blockIdx.x * 128;
    const int tid = threadIdx.x;

    for (int it = tid; it < 128 * 16; it += 256) {
        int r = it >> 4, ch = it & 15;
        *(uint4*)&As[r][ch * 8] = *(const uint4*)(attn_out + (size_t)(m0 + r) * CDIM + ch * 8);
    }
    for (int it = tid; it < 128 * 16; it += 256) {
        int r = it >> 4, ch = it & 15;
        *(uint4*)&Bs[r][ch * 8] = *(const uint4*)(Wtp + (size_t)r * 128 + ch * 8);
    }
    __syncthreads();

    const int lane = tid & 63, wv = tid >> 6;
    const int wr = wv >> 1, wc = wv & 1;
    const int c = lane & 15, quad = lane >> 4;

    f32x4 acc[4][4];
#pragma unroll
    for (int i = 0; i < 4; i++)
#pragma unroll
        for (int j = 0; j < 4; j++) acc[i][j] = (f32x4){0.f, 0.f, 0.f, 0.f};

#pragma unroll
    for (int kc = 0; kc < 4; kc++) {
        bf16x8 a[4], b[4];
#pragma unroll
        for (int i = 0; i < 4; i++) a[i] = *(const bf16x8*)&As[wr * 64 + i * 16 + c][kc * 32 + quad * 8];
#pragma unroll
        for (int j = 0; j < 4; j++) b[j] = *(const bf16x8*)&Bs[wc * 64 + j * 16 + c][kc * 32 + quad * 8];
#pragma unroll
        for (int i = 0; i < 4; i++)
#pragma unroll
            for (int j = 0; j < 4; j++)
                acc[i][j] = __builtin_amdgcn_mfma_f32_16x16x32_bf16(a[i], b[j], acc[i][j], 0, 0, 0);
    }

#pragma unroll
    for (int j = 0; j < 4; j++) {
        int col = wc * 64 + j * 16 + c;
        float bias = bproj[col];
#pragma unroll
        for (int i = 0; i < 4; i++) {
            int row0 = m0 + wr * 64 + i * 16 + quad * 4;
            int bidx = row0 / 69, n = row0 - bidx * 69;
#pragma unroll
            for (int rr = 0; rr < 4; rr++) {
                float val = acc[i][j][rr] + bias;
                if (n >= PLEN)
                    x_out[((size_t)bidx * NWIN + (n - PLEN)) * CDIM + col] = val;
                else
                    promptproj[((size_t)bidx * PLEN + n) * CDIM + col] = val;
                if (++n == 69) { n = 0; ++bidx; }
            }
        }
    }
}

// ---------- prompt mean over 64 windows ----------
__global__ __launch_bounds__(256) void mean_kernel(
    const float* __restrict__ promptproj, float* __restrict__ prompts_out)
{
    int idx = blockIdx.x * 256 + threadIdx.x;
    if (idx >= BGRP * PLEN * CDIM) return;
    int c = idx & 127;
    int p = (idx >> 7) % PLEN;
    int bb = idx / (PLEN * CDIM);
    size_t base = (((size_t)bb * NW) * PLEN + p) * CDIM + c;
    float s = 0.f;
    for (int w = 0; w < NW; w++) s += promptproj[base + (size_t)w * (PLEN * CDIM)];
    prompts_out[idx] = s * (1.f / 64.f);
}

extern "C" void kernel_launch(void* const* d_in, const int* in_sizes, int n_in,
                              void* d_out, int out_size, void* d_ws, size_t ws_size,
                              hipStream_t stream)
{
    const float* x       = (const float*)d_in[0];
    const float* prompts = (const float*)d_in[1];
    const float* mask    = (const float*)d_in[2];
    const float* relb    = (const float*)d_in[3];
    const float* Wqkv    = (const float*)d_in[4];
    const float* bqkv    = (const float*)d_in[5];
    const float* Wproj   = (const float*)d_in[6];
    const float* bproj   = (const float*)d_in[7];

    float* out = (float*)d_out;
    float* x_out       = out;
    float* ori_w       = out + (size_t)B_TOT * NWIN * CDIM;
    float* prompts_out = ori_w + (size_t)B_TOT * NH * PLEN * NWIN;

    char* wsb = (char*)d_ws;
    size_t off = 0;
    const size_t winQKV = (size_t)B_TOT * NH * NWIN * HD;   // ushort count
    const size_t pQKV   = (size_t)BGRP * NH * PLEN * HD;
    ushort_t* q_win = (ushort_t*)(wsb + off); off += winQKV * 2;
    ushort_t* k_win = (ushort_t*)(wsb + off); off += winQKV * 2;
    ushort_t* v_win = (ushort_t*)(wsb + off); off += winQKV * 2;
    ushort_t* q_p   = (ushort_t*)(wsb + off); off += pQKV * 2;
    ushort_t* k_p   = (ushort_t*)(wsb + off); off += pQKV * 2;
    ushort_t* v_p   = (ushort_t*)(wsb + off); off += pQKV * 2;
    ushort_t* attn_o = (ushort_t*)(wsb + off); off += (size_t)B_TOT * NTOK * CDIM * 2;
    float* promptproj = (float*)(wsb + off); off += (size_t)B_TOT * PLEN * CDIM * 4;
    float* bm = (float*)(wsb + off); off += (size_t)NW * NH * 49 * 49 * 4;
    ushort_t* Wtq = (ushort_t*)(wsb + off); off += 384 * 128 * 2;
    ushort_t* Wtp = (ushort_t*)(wsb + off); off += 128 * 128 * 2;

    convw_kernel<<<256, 256, 0, stream>>>(Wqkv, Wproj, Wtq, Wtp);
    bm_kernel<<<(NW * NH * 49 * 49) / 256, 256, 0, stream>>>(relb, mask, bm);
    qkv_kernel<<<dim3(TOT_ROWS / 128, 3), 256, 0, stream>>>(x, prompts, Wtq, bqkv,
                                                            q_win, k_win, v_win, q_p, k_p, v_p);
    attn_kernel<<<B_TOT * NH, 256, 0, stream>>>(q_win, k_win, v_win, q_p, k_p, v_p,
                                                bm, attn_o, ori_w);
    proj_kernel<<<PROJ_ROWS / 128, 256, 0, stream>>>(attn_o, Wtp, bproj, x_out, promptproj);
    mean_kernel<<<(BGRP * PLEN * CDIM + 255) / 256, 256, 0, stream>>>(promptproj, prompts_out);
}

// Round 5
// 269.703 us; speedup vs baseline: 2.7142x; 1.1352x over previous
//
#include <hip/hip_runtime.h>
#include <hip/hip_bf16.h>

#define B_TOT   2048
#define BGRP    32
#define NW      64
#define NWIN    49
#define PLEN    20
#define NTOK    69
#define CDIM    128
#define NH      4
#define HD      32
#define SCALE_F 0.17677669529663687f

#define WIN_ROWS (B_TOT * NWIN)            // 100352 = 784*128
#define PROMPT_ROWS (BGRP * PLEN)          // 640
#define TOT_ROWS (WIN_ROWS + PROMPT_ROWS)  // 100992 = 789*128
#define PROJ_ROWS (B_TOT * NTOK)           // 141312 = 1104*128

typedef unsigned short ushort_t;
typedef __attribute__((ext_vector_type(8))) short bf16x8;
typedef __attribute__((ext_vector_type(4))) float f32x4;

__device__ __forceinline__ ushort_t f2b(float f) {
    union { float f; unsigned u; } v; v.f = f;
    unsigned r = v.u + 0x7FFFu + ((v.u >> 16) & 1u);
    return (ushort_t)(r >> 16);
}

// ---------- prep: transpose+convert weights to bf16 ----------
__global__ __launch_bounds__(256) void convw_kernel(
    const float* __restrict__ Wqkv, const float* __restrict__ Wproj,
    ushort_t* __restrict__ Wtq, ushort_t* __restrict__ Wtp)
{
    int idx = blockIdx.x * 256 + threadIdx.x;   // < 65536
    if (idx < 384 * 128) {
        int n = idx >> 7, k = idx & 127;
        Wtq[idx] = f2b(Wqkv[k * 384 + n]);
    } else {
        int i = idx - 384 * 128;
        int n = i >> 7, k = i & 127;
        Wtp[i] = f2b(Wproj[k * 128 + n]);
    }
}

// ---------- prep: fused rel-bias + mask table bm[(w*4+h)][ii][jj] ----------
__global__ __launch_bounds__(256) void bm_kernel(
    const float* __restrict__ relb, const float* __restrict__ mask, float* __restrict__ bm)
{
    int idx = blockIdx.x * 256 + threadIdx.x;   // < 614656
    int jj = idx % 49; int t = idx / 49; int ii = t % 49; int wh = t / 49;
    int h = wh & 3, w = wh >> 2;
    int ridx = (ii / 7 - jj / 7 + 6) * 13 + (ii % 7 - jj % 7 + 6);
    bm[idx] = relb[ridx * NH + h] + mask[((size_t)w * 49 + ii) * 49 + jj];
}

// ---------- QKV: 128x128 MFMA tile; outputs ROW-MAJOR [token][128] bf16 ----------
__global__ __launch_bounds__(256) void qkv_kernel(
    const float* __restrict__ x, const float* __restrict__ prompts,
    const ushort_t* __restrict__ Wtq, const float* __restrict__ bqkv,
    ushort_t* __restrict__ q_win, ushort_t* __restrict__ k_win, ushort_t* __restrict__ v_win,
    ushort_t* __restrict__ q_p, ushort_t* __restrict__ k_p, ushort_t* __restrict__ v_p)
{
    __shared__ __align__(16) ushort_t As[128][136];
    __shared__ __align__(16) ushort_t Bs[128][136];
    const int m0 = blockIdx.x * 128;
    const int by = blockIdx.y;
    const int tid = threadIdx.x;

    for (int it = tid; it < 128 * 16; it += 256) {
        int r = it >> 4, ch = it & 15;
        int row = m0 + r;
        const float* src = (row < WIN_ROWS) ? x + (size_t)row * CDIM + ch * 8
                                            : prompts + (size_t)(row - WIN_ROWS) * CDIM + ch * 8;
        float4 v0 = *(const float4*)src;
        float4 v1 = *(const float4*)(src + 4);
        ushort_t tmp[8] = {f2b(v0.x), f2b(v0.y), f2b(v0.z), f2b(v0.w),
                           f2b(v1.x), f2b(v1.y), f2b(v1.z), f2b(v1.w)};
        *(uint4*)&As[r][ch * 8] = *(uint4*)tmp;
    }
    for (int it = tid; it < 128 * 16; it += 256) {
        int r = it >> 4, ch = it & 15;
        *(uint4*)&Bs[r][ch * 8] = *(const uint4*)(Wtq + ((size_t)(by * 128 + r)) * 128 + ch * 8);
    }
    __syncthreads();

    const int lane = tid & 63, wv = tid >> 6;
    const int wr = wv >> 1, wc = wv & 1;
    const int c = lane & 15, quad = lane >> 4;

    f32x4 acc[4][4];
#pragma unroll
    for (int i = 0; i < 4; i++)
#pragma unroll
        for (int j = 0; j < 4; j++) acc[i][j] = (f32x4){0.f, 0.f, 0.f, 0.f};

#pragma unroll
    for (int kc = 0; kc < 4; kc++) {
        bf16x8 a[4], b[4];
#pragma unroll
        for (int i = 0; i < 4; i++) a[i] = *(const bf16x8*)&As[wr * 64 + i * 16 + c][kc * 32 + quad * 8];
#pragma unroll
        for (int j = 0; j < 4; j++) b[j] = *(const bf16x8*)&Bs[wc * 64 + j * 16 + c][kc * 32 + quad * 8];
#pragma unroll
        for (int i = 0; i < 4; i++)
#pragma unroll
            for (int j = 0; j < 4; j++)
                acc[i][j] = __builtin_amdgcn_mfma_f32_16x16x32_bf16(a[i], b[j], acc[i][j], 0, 0, 0);
    }

    // epilogue: acc -> LDS (bf16) -> coalesced row writes
    __syncthreads();
    ushort_t* Os = &As[0][0];
#pragma unroll
    for (int j = 0; j < 4; j++) {
        int col = wc * 64 + j * 16 + c;
        float bias = bqkv[by * 128 + col];
#pragma unroll
        for (int i = 0; i < 4; i++) {
            int rl = wr * 64 + i * 16 + quad * 4;
#pragma unroll
            for (int rr = 0; rr < 4; rr++)
                Os[(rl + rr) * 136 + col] = f2b(acc[i][j][rr] + bias);
        }
    }
    __syncthreads();

    ushort_t* dw = (by == 0) ? q_win : (by == 1) ? k_win : v_win;
    ushort_t* dp = (by == 0) ? q_p   : (by == 1) ? k_p   : v_p;
    for (int it = tid; it < 128 * 16; it += 256) {
        int r = it >> 4, ch = it & 15;
        int row = m0 + r;
        uint4 val = *(uint4*)&Os[r * 136 + ch * 8];
        if (row < WIN_ROWS) *(uint4*)&dw[(size_t)row * CDIM + ch * 8] = val;
        else                *(uint4*)&dp[(size_t)(row - WIN_ROWS) * CDIM + ch * 8] = val;
    }
}

// ---------- fused attention: 1 block = 1 window, wave = head ----------
__global__ __launch_bounds__(256, 3) void attn_kernel(
    const ushort_t* __restrict__ q_win, const ushort_t* __restrict__ k_win, const ushort_t* __restrict__ v_win,
    const ushort_t* __restrict__ q_p, const ushort_t* __restrict__ k_p, const ushort_t* __restrict__ v_p,
    const float* __restrict__ bm,
    ushort_t* __restrict__ attn_out, float* __restrict__ ori_w)
{
    __shared__ __align__(16) ushort_t Vt[4][32][104];   // per head: V^T [d][key], keys 69..95 zero
    __shared__ __align__(16) ushort_t Ps[4][16][104];   // per head: current-tile P, cols 80..95 zero

    const int b = blockIdx.x;
    const int bb = b >> 6;
    const int w = b & 63;
    const int tid = threadIdx.x;

    // zero Ps cols 80..95 (stay zero: softmax only writes cols < 80)
    for (int it = tid; it < 64 * 2; it += 256) {
        int row = it >> 1, half = it & 1;
        *(uint4*)&Ps[row >> 4][row & 15][80 + half * 8] = (uint4){0u, 0u, 0u, 0u};
    }
    // zero Vt key-cols 69..95
    for (int it = tid; it < 128 * 27; it += 256) {
        int d = it / 27, cc = 69 + it % 27;
        Vt[d >> 5][d & 31][cc] = 0;
    }
    // stage V transposed (coalesced global reads; scalar LDS transpose writes)
    for (int it = tid; it < 69 * 16; it += 256) {
        int n = it >> 4, ch = it & 15;
        const ushort_t* vb = (n < PLEN) ? v_p + ((size_t)bb * PLEN + n) * CDIM
                                        : v_win + ((size_t)b * NWIN + (n - PLEN)) * CDIM;
        uint4 vv = *(const uint4*)(vb + ch * 8);
        ushort_t tmp[8]; *(uint4*)tmp = vv;
        int hh = ch >> 2, dbase = (ch & 3) * 8;
#pragma unroll
        for (int i = 0; i < 8; i++) Vt[hh][dbase + i][n] = tmp[i];
    }
    __syncthreads();

    const int lane = tid & 63, h = tid >> 6;
    const int c = lane & 15, quad = lane >> 4;
    const int dsl = h * HD + quad * 8;     // this lane's 8-wide d-slice within the row

    // K fragments straight from global (reused across all 5 q-tiles)
    bf16x8 kf[5];
#pragma unroll
    for (int j = 0; j < 5; j++) {
        int n = j * 16 + c; if (n > 68) n = 68;
        const ushort_t* kb = (n < PLEN) ? k_p + ((size_t)bb * PLEN + n) * CDIM
                                        : k_win + ((size_t)b * NWIN + (n - PLEN)) * CDIM;
        kf[j] = *(const bf16x8*)(kb + dsl);
    }
    // V fragments from LDS (reused across all 5 q-tiles)
    bf16x8 vf[2][3];
#pragma unroll
    for (int dt = 0; dt < 2; dt++)
#pragma unroll
        for (int kc = 0; kc < 3; kc++)
            vf[dt][kc] = *(const bf16x8*)&Vt[h][dt * 16 + c][kc * 32 + quad * 8];

    const float* bmw = bm + (size_t)(w * NH + h) * (49 * 49);

    for (int itile = 0; itile < 5; itile++) {
        int nq = itile * 16 + c; if (nq > 68) nq = 68;
        const ushort_t* qb = (nq < PLEN) ? q_p + ((size_t)bb * PLEN + nq) * CDIM
                                         : q_win + ((size_t)b * NWIN + (nq - PLEN)) * CDIM;
        bf16x8 qf = *(const bf16x8*)(qb + dsl);

        f32x4 s[5];
#pragma unroll
        for (int j = 0; j < 5; j++)
            s[j] = __builtin_amdgcn_mfma_f32_16x16x32_bf16(qf, kf[j], (f32x4){0.f, 0.f, 0.f, 0.f}, 0, 0, 0);

        const int mbase = itile * 16 + quad * 4;

        // raw scores -> ori_attn_weight (prompt queries x window keys)
        if (mbase < 20) {
#pragma unroll
            for (int j = 1; j < 5; j++) {
                int col = j * 16 + c;
                if (col >= 20 && col < 69) {
#pragma unroll
                    for (int rr = 0; rr < 4; rr++) {
                        int m = mbase + rr;
                        if (m < 20)
                            ori_w[(((size_t)b * NH + h) * PLEN + m) * NWIN + (col - 20)] = s[j][rr];
                    }
                }
            }
        }
        // scale + fused bias/mask; pad cols -> -inf
#pragma unroll
        for (int j = 0; j < 5; j++) {
            int col = j * 16 + c;
#pragma unroll
            for (int rr = 0; rr < 4; rr++) {
                int m = mbase + rr;
                float v;
                if (col >= 69) v = -1e30f;
                else {
                    v = s[j][rr] * SCALE_F;
                    if (m >= 20 && m < 69 && col >= 20)
                        v += bmw[(m - 20) * 49 + (col - 20)];
                }
                s[j][rr] = v;
            }
        }
        // in-register softmax (row = quad*4+rr, 16 lanes share a row)
#pragma unroll
        for (int rr = 0; rr < 4; rr++) {
            float mx = fmaxf(fmaxf(fmaxf(s[0][rr], s[1][rr]), fmaxf(s[2][rr], s[3][rr])), s[4][rr]);
            mx = fmaxf(mx, __shfl_xor(mx, 1));
            mx = fmaxf(mx, __shfl_xor(mx, 2));
            mx = fmaxf(mx, __shfl_xor(mx, 4));
            mx = fmaxf(mx, __shfl_xor(mx, 8));
            float e0 = __expf(s[0][rr] - mx), e1 = __expf(s[1][rr] - mx), e2 = __expf(s[2][rr] - mx);
            float e3 = __expf(s[3][rr] - mx), e4 = __expf(s[4][rr] - mx);
            float sum = e0 + e1 + e2 + e3 + e4;
            sum += __shfl_xor(sum, 1);
            sum += __shfl_xor(sum, 2);
            sum += __shfl_xor(sum, 4);
            sum += __shfl_xor(sum, 8);
            float inv = 1.f / sum;
            int mrow = quad * 4 + rr;
            Ps[h][mrow][c]      = f2b(e0 * inv);
            Ps[h][mrow][16 + c] = f2b(e1 * inv);
            Ps[h][mrow][32 + c] = f2b(e2 * inv);
            Ps[h][mrow][48 + c] = f2b(e3 * inv);
            Ps[h][mrow][64 + c] = f2b(e4 * inv);
        }
        // PV for this tile (wave-private Ps; no barrier needed)
#pragma unroll
        for (int dt = 0; dt < 2; dt++) {
            f32x4 o = {0.f, 0.f, 0.f, 0.f};
#pragma unroll
            for (int kc = 0; kc < 3; kc++) {
                bf16x8 pa = *(const bf16x8*)&Ps[h][c][kc * 32 + quad * 8];
                o = __builtin_amdgcn_mfma_f32_16x16x32_bf16(pa, vf[dt][kc], o, 0, 0, 0);
            }
#pragma unroll
            for (int rr = 0; rr < 4; rr++) {
                int m = mbase + rr;
                if (m < 69)
                    attn_out[((size_t)b * NTOK + m) * CDIM + h * HD + dt * 16 + c] = f2b(o[rr]);
            }
        }
    }
}

// ---------- proj: 128x128 MFMA GEMM, LDS-staged f32 epilogue ----------
__global__ __launch_bounds__(256) void proj_kernel(
    const ushort_t* __restrict__ attn_out, const ushort_t* __restrict__ Wtp,
    const float* __restrict__ bproj,
    float* __restrict__ x_out, float* __restrict__ promptproj)
{
    __shared__ __align__(16) char smem[128 * 136 * 4];
    ushort_t (*As)[136] = (ushort_t(*)[136])smem;
    ushort_t (*Bs)[136] = (ushort_t(*)[136])(smem + 128 * 136 * 2);
    float (*Osf)[136] = (float(*)[136])smem;

    const int m0 = blockIdx.x * 128;
    const int tid = threadIdx.x;

    for (int it = tid; it < 128 * 16; it += 256) {
        int r = it >> 4, ch = it & 15;
        *(uint4*)&As[r][ch * 8] = *(const uint4*)(attn_out + (size_t)(m0 + r) * CDIM + ch * 8);
    }
    for (int it = tid; it < 128 * 16; it += 256) {
        int r = it >> 4, ch = it & 15;
        *(uint4*)&Bs[r][ch * 8] = *(const uint4*)(Wtp + (size_t)r * 128 + ch * 8);
    }
    __syncthreads();

    const int lane = tid & 63, wv = tid >> 6;
    const int wr = wv >> 1, wc = wv & 1;
    const int c = lane & 15, quad = lane >> 4;

    f32x4 acc[4][4];
#pragma unroll
    for (int i = 0; i < 4; i++)
#pragma unroll
        for (int j = 0; j < 4; j++) acc[i][j] = (f32x4){0.f, 0.f, 0.f, 0.f};

#pragma unroll
    for (int kc = 0; kc < 4; kc++) {
        bf16x8 a[4], b[4];
#pragma unroll
        for (int i = 0; i < 4; i++) a[i] = *(const bf16x8*)&As[wr * 64 + i * 16 + c][kc * 32 + quad * 8];
#pragma unroll
        for (int j = 0; j < 4; j++) b[j] = *(const bf16x8*)&Bs[wc * 64 + j * 16 + c][kc * 32 + quad * 8];
#pragma unroll
        for (int i = 0; i < 4; i++)
#pragma unroll
            for (int j = 0; j < 4; j++)
                acc[i][j] = __builtin_amdgcn_mfma_f32_16x16x32_bf16(a[i], b[j], acc[i][j], 0, 0, 0);
    }

    __syncthreads();
#pragma unroll
    for (int j = 0; j < 4; j++) {
        int col = wc * 64 + j * 16 + c;
        float bias = bproj[col];
#pragma unroll
        for (int i = 0; i < 4; i++) {
            int rl = wr * 64 + i * 16 + quad * 4;
#pragma unroll
            for (int rr = 0; rr < 4; rr++)
                Osf[rl + rr][col] = acc[i][j][rr] + bias;
        }
    }
    __syncthreads();

    for (int it = tid; it < 128 * 32; it += 256) {
        int r = it >> 5, ch = it & 31;
        float4 val = *(float4*)&Osf[r][ch * 4];
        int row = m0 + r;
        int bidx = row / NTOK, n = row - bidx * NTOK;
        if (n >= PLEN)
            *(float4*)&x_out[((size_t)bidx * NWIN + (n - PLEN)) * CDIM + ch * 4] = val;
        else
            *(float4*)&promptproj[((size_t)bidx * PLEN + n) * CDIM + ch * 4] = val;
    }
}

// ---------- prompt mean over 64 windows ----------
__global__ __launch_bounds__(256) void mean_kernel(
    const float* __restrict__ promptproj, float* __restrict__ prompts_out)
{
    int idx = blockIdx.x * 256 + threadIdx.x;
    if (idx >= BGRP * PLEN * CDIM) return;
    int c = idx & 127;
    int p = (idx >> 7) % PLEN;
    int bb = idx / (PLEN * CDIM);
    size_t base = (((size_t)bb * NW) * PLEN + p) * CDIM + c;
    float s = 0.f;
    for (int w = 0; w < NW; w++) s += promptproj[base + (size_t)w * (PLEN * CDIM)];
    prompts_out[idx] = s * (1.f / 64.f);
}

extern "C" void kernel_launch(void* const* d_in, const int* in_sizes, int n_in,
                              void* d_out, int out_size, void* d_ws, size_t ws_size,
                              hipStream_t stream)
{
    const float* x       = (const float*)d_in[0];
    const float* prompts = (const float*)d_in[1];
    const float* mask    = (const float*)d_in[2];
    const float* relb    = (const float*)d_in[3];
    const float* Wqkv    = (const float*)d_in[4];
    const float* bqkv    = (const float*)d_in[5];
    const float* Wproj   = (const float*)d_in[6];
    const float* bproj   = (const float*)d_in[7];

    float* out = (float*)d_out;
    float* x_out       = out;
    float* ori_w       = out + (size_t)B_TOT * NWIN * CDIM;
    float* prompts_out = ori_w + (size_t)B_TOT * NH * PLEN * NWIN;

    char* wsb = (char*)d_ws;
    size_t off = 0;
    const size_t winQKV = (size_t)WIN_ROWS * CDIM;     // ushort count
    const size_t pQKV   = (size_t)PROMPT_ROWS * CDIM;
    ushort_t* q_win = (ushort_t*)(wsb + off); off += winQKV * 2;
    ushort_t* k_win = (ushort_t*)(wsb + off); off += winQKV * 2;
    ushort_t* v_win = (ushort_t*)(wsb + off); off += winQKV * 2;
    ushort_t* q_p   = (ushort_t*)(wsb + off); off += pQKV * 2;
    ushort_t* k_p   = (ushort_t*)(wsb + off); off += pQKV * 2;
    ushort_t* v_p   = (ushort_t*)(wsb + off); off += pQKV * 2;
    ushort_t* attn_o = (ushort_t*)(wsb + off); off += (size_t)PROJ_ROWS * CDIM * 2;
    float* promptproj = (float*)(wsb + off); off += (size_t)B_TOT * PLEN * CDIM * 4;
    float* bm = (float*)(wsb + off); off += (size_t)NW * NH * 49 * 49 * 4;
    ushort_t* Wtq = (ushort_t*)(wsb + off); off += 384 * 128 * 2;
    ushort_t* Wtp = (ushort_t*)(wsb + off); off += 128 * 128 * 2;

    convw_kernel<<<256, 256, 0, stream>>>(Wqkv, Wproj, Wtq, Wtp);
    bm_kernel<<<(NW * NH * 49 * 49) / 256, 256, 0, stream>>>(relb, mask, bm);
    qkv_kernel<<<dim3(TOT_ROWS / 128, 3), 256, 0, stream>>>(x, prompts, Wtq, bqkv,
                                                            q_win, k_win, v_win, q_p, k_p, v_p);
    attn_kernel<<<B_TOT, 256, 0, stream>>>(q_win, k_win, v_win, q_p, k_p, v_p,
                                           bm, attn_o, ori_w);
    proj_kernel<<<PROJ_ROWS / 128, 256, 0, stream>>>(attn_o, Wtp, bproj, x_out, promptproj);
    mean_kernel<<<(BGRP * PLEN * CDIM + 255) / 256, 256, 0, stream>>>(promptproj, prompts_out);
}

// Round 6
// 254.003 us; speedup vs baseline: 2.8820x; 1.0618x over previous
//
#include <hip/hip_runtime.h>
#include <hip/hip_bf16.h>

#define B_TOT   2048
#define BGRP    32
#define NW      64
#define NWIN    49
#define PLEN    20
#define NTOK    69
#define CDIM    128
#define NH      4
#define HD      32
#define SCALE_F 0.17677669529663687f

#define WIN_ROWS (B_TOT * NWIN)            // 100352 = 784*128
#define PROMPT_ROWS (BGRP * PLEN)          // 640
#define TOT_ROWS (WIN_ROWS + PROMPT_ROWS)  // 100992 = 789*128
#define PROJ_ROWS (B_TOT * NTOK)           // 141312 = 1104*128

typedef unsigned short ushort_t;
typedef __attribute__((ext_vector_type(8))) short bf16x8;
typedef __attribute__((ext_vector_type(4))) float f32x4;

__device__ __forceinline__ ushort_t f2b(float f) {
    union { float f; unsigned u; } v; v.f = f;
    unsigned r = v.u + 0x7FFFu + ((v.u >> 16) & 1u);
    return (ushort_t)(r >> 16);
}

// element-index XOR swizzle: spreads stride-128 (2B elem) rows across banks
__device__ __forceinline__ int swz(int row, int col) { return col ^ ((row & 7) << 3); }

// ---------- prep: transpose+convert weights to bf16 ----------
__global__ __launch_bounds__(256) void convw_kernel(
    const float* __restrict__ Wqkv, const float* __restrict__ Wproj,
    ushort_t* __restrict__ Wtq, ushort_t* __restrict__ Wtp)
{
    int idx = blockIdx.x * 256 + threadIdx.x;   // < 65536
    if (idx < 384 * 128) {
        int n = idx >> 7, k = idx & 127;
        Wtq[idx] = f2b(Wqkv[k * 384 + n]);
    } else {
        int i = idx - 384 * 128;
        int n = i >> 7, k = i & 127;
        Wtp[i] = f2b(Wproj[k * 128 + n]);
    }
}

// ---------- prep: padded bias+mask table bm80[(w*4+h)][row 0..79][col 0..79] ----------
__global__ __launch_bounds__(256) void bm80_kernel(
    const float* __restrict__ relb, const float* __restrict__ mask, float* __restrict__ bm80)
{
    int idx = blockIdx.x * 256 + threadIdx.x;   // < 64*4*80*80 = 1638400
    int col = idx % 80; int t = idx / 80; int row = t % 80; int wh = t / 80;
    int h = wh & 3, w = wh >> 2;
    float v;
    if (col >= 69)      v = (row < 69) ? -1e30f : 0.f;   // pad cols excluded for real rows
    else if (row < 20 || col < 20 || row >= 69) v = 0.f; // prompt rows/cols: no bias/mask
    else {
        int ii = row - 20, jj = col - 20;
        int ridx = (ii / 7 - jj / 7 + 6) * 13 + (ii % 7 - jj % 7 + 6);
        v = relb[ridx * NH + h] + mask[((size_t)w * 49 + ii) * 49 + jj];
    }
    bm80[idx] = v;
}

// ---------- QKV: single pass over x; 3 N-chunks inner loop ----------
__global__ __launch_bounds__(256) void qkv_kernel(
    const float* __restrict__ x, const float* __restrict__ prompts,
    const ushort_t* __restrict__ Wtq, const float* __restrict__ bqkv,
    ushort_t* __restrict__ q_win, ushort_t* __restrict__ k_win, ushort_t* __restrict__ v_win,
    ushort_t* __restrict__ q_p, ushort_t* __restrict__ k_p, ushort_t* __restrict__ v_p)
{
    __shared__ __align__(16) ushort_t As[128][136];
    __shared__ __align__(16) ushort_t Bs[128][136];
    const int m0 = blockIdx.x * 128;
    const int tid = threadIdx.x;

    // stage A (f2b) ONCE
    for (int it = tid; it < 128 * 16; it += 256) {
        int r = it >> 4, ch = it & 15;
        int row = m0 + r;
        const float* src = (row < WIN_ROWS) ? x + (size_t)row * CDIM + ch * 8
                                            : prompts + (size_t)(row - WIN_ROWS) * CDIM + ch * 8;
        float4 v0 = *(const float4*)src;
        float4 v1 = *(const float4*)(src + 4);
        ushort_t tmp[8] = {f2b(v0.x), f2b(v0.y), f2b(v0.z), f2b(v0.w),
                           f2b(v1.x), f2b(v1.y), f2b(v1.z), f2b(v1.w)};
        *(uint4*)&As[r][ch * 8] = *(uint4*)tmp;
    }
    __syncthreads();

    const int lane = tid & 63, wv = tid >> 6;
    const int wr = wv >> 1, wc = wv & 1;
    const int c = lane & 15, quad = lane >> 4;

    // hoist all A fragments to registers (reused for all 3 chunks)
    bf16x8 af[4][4];   // [kc][i]
#pragma unroll
    for (int kc = 0; kc < 4; kc++)
#pragma unroll
        for (int i = 0; i < 4; i++)
            af[kc][i] = *(const bf16x8*)&As[wr * 64 + i * 16 + c][kc * 32 + quad * 8];

    for (int chunk = 0; chunk < 3; chunk++) {
        for (int it = tid; it < 128 * 16; it += 256) {
            int r = it >> 4, ch = it & 15;
            *(uint4*)&Bs[r][ch * 8] =
                *(const uint4*)(Wtq + ((size_t)(chunk * 128 + r)) * 128 + ch * 8);
        }
        __syncthreads();

        f32x4 acc[4][4];
#pragma unroll
        for (int i = 0; i < 4; i++)
#pragma unroll
            for (int j = 0; j < 4; j++) acc[i][j] = (f32x4){0.f, 0.f, 0.f, 0.f};

#pragma unroll
        for (int kc = 0; kc < 4; kc++) {
            bf16x8 b[4];
#pragma unroll
            for (int j = 0; j < 4; j++)
                b[j] = *(const bf16x8*)&Bs[wc * 64 + j * 16 + c][kc * 32 + quad * 8];
#pragma unroll
            for (int i = 0; i < 4; i++)
#pragma unroll
                for (int j = 0; j < 4; j++)
                    acc[i][j] = __builtin_amdgcn_mfma_f32_16x16x32_bf16(af[kc][i], b[j], acc[i][j], 0, 0, 0);
        }
        __syncthreads();

        // epilogue: acc -> Bs(bf16) -> coalesced row writes
        ushort_t* Os = &Bs[0][0];
#pragma unroll
        for (int j = 0; j < 4; j++) {
            int col = wc * 64 + j * 16 + c;
            float bias = bqkv[chunk * 128 + col];
#pragma unroll
            for (int i = 0; i < 4; i++) {
                int rl = wr * 64 + i * 16 + quad * 4;
#pragma unroll
                for (int rr = 0; rr < 4; rr++)
                    Os[(rl + rr) * 136 + col] = f2b(acc[i][j][rr] + bias);
            }
        }
        __syncthreads();

        ushort_t* dw = (chunk == 0) ? q_win : (chunk == 1) ? k_win : v_win;
        ushort_t* dp = (chunk == 0) ? q_p   : (chunk == 1) ? k_p   : v_p;
        for (int it = tid; it < 128 * 16; it += 256) {
            int r = it >> 4, ch = it & 15;
            int row = m0 + r;
            uint4 val = *(uint4*)&Os[r * 136 + ch * 8];
            if (row < WIN_ROWS) *(uint4*)&dw[(size_t)row * CDIM + ch * 8] = val;
            else                *(uint4*)&dp[(size_t)(row - WIN_ROWS) * CDIM + ch * 8] = val;
        }
        __syncthreads();   // protect Bs before next chunk's load
    }
}

// ---------- fused attention: 1 block = 1 window, wave = head; swizzled LDS ----------
__global__ __launch_bounds__(256, 3) void attn_kernel(
    const ushort_t* __restrict__ q_win, const ushort_t* __restrict__ k_win, const ushort_t* __restrict__ v_win,
    const ushort_t* __restrict__ q_p, const ushort_t* __restrict__ k_p, const ushort_t* __restrict__ v_p,
    const float* __restrict__ bm80,
    ushort_t* __restrict__ attn_out, float* __restrict__ ori_w)
{
    __shared__ __align__(16) ushort_t Vt[4][32][128];   // per head: V^T [d][key], swizzled
    __shared__ __align__(16) ushort_t Ps[4][16][128];   // per head: current-tile P, swizzled

    const int b = blockIdx.x;
    const int bb = b >> 6;
    const int w = b & 63;
    const int tid = threadIdx.x;

    // zero Vt key-cols 69..95 (swizzled positions)
    for (int it = tid; it < 4 * 32 * 27; it += 256) {
        int hh = it / (32 * 27), rem = it % (32 * 27);
        int d = rem / 27, cc = 69 + rem % 27;
        Vt[hh][d][swz(d, cc)] = 0;
    }
    // zero Ps key-cols 80..95 (stay zero across all itiles)
    for (int it = tid; it < 4 * 16 * 16; it += 256) {
        int hh = it >> 8, rem = it & 255;
        int r = rem >> 4, cc = 80 + (rem & 15);
        Ps[hh][r][swz(r, cc)] = 0;
    }
    // stage V transposed (coalesced global reads; swizzled scalar LDS writes)
    for (int it = tid; it < 69 * 16; it += 256) {
        int n = it >> 4, ch = it & 15;
        const ushort_t* vb = (n < PLEN) ? v_p + ((size_t)bb * PLEN + n) * CDIM
                                        : v_win + ((size_t)b * NWIN + (n - PLEN)) * CDIM;
        uint4 vv = *(const uint4*)(vb + ch * 8);
        ushort_t tmp[8]; *(uint4*)tmp = vv;
        int hh = ch >> 2, dbase = (ch & 3) * 8;
#pragma unroll
        for (int i = 0; i < 8; i++) {
            int d = dbase + i;
            Vt[hh][d][swz(d, n)] = tmp[i];
        }
    }
    __syncthreads();

    const int lane = tid & 63, h = tid >> 6;
    const int c = lane & 15, quad = lane >> 4;
    const int dsl = h * HD + quad * 8;
    const int xk_rd = (c & 7) << 3;        // read-side swizzle key (row = c)

    // K fragments straight from global (reused across all 5 q-tiles)
    bf16x8 kf[5];
#pragma unroll
    for (int j = 0; j < 5; j++) {
        int n = j * 16 + c; if (n > 68) n = 68;
        const ushort_t* kb = (n < PLEN) ? k_p + ((size_t)bb * PLEN + n) * CDIM
                                        : k_win + ((size_t)b * NWIN + (n - PLEN)) * CDIM;
        kf[j] = *(const bf16x8*)(kb + dsl);
    }
    // V fragments from LDS (rows d = dt*16+c -> row&7 == c&7)
    bf16x8 vf[2][3];
#pragma unroll
    for (int dt = 0; dt < 2; dt++)
#pragma unroll
        for (int kc = 0; kc < 3; kc++)
            vf[dt][kc] = *(const bf16x8*)&Vt[h][dt * 16 + c][(kc * 32 + quad * 8) ^ xk_rd];

    const float* bmw = bm80 + (size_t)(w * NH + h) * 6400;

    for (int itile = 0; itile < 5; itile++) {
        int nq = itile * 16 + c; if (nq > 68) nq = 68;
        const ushort_t* qb = (nq < PLEN) ? q_p + ((size_t)bb * PLEN + nq) * CDIM
                                         : q_win + ((size_t)b * NWIN + (nq - PLEN)) * CDIM;
        bf16x8 qf = *(const bf16x8*)(qb + dsl);

        f32x4 s[5];
#pragma unroll
        for (int j = 0; j < 5; j++)
            s[j] = __builtin_amdgcn_mfma_f32_16x16x32_bf16(qf, kf[j], (f32x4){0.f, 0.f, 0.f, 0.f}, 0, 0, 0);

        const int mbase = itile * 16 + quad * 4;

        // raw scores -> ori_attn_weight (prompt queries x window keys)
        if (mbase < 20) {
#pragma unroll
            for (int j = 1; j < 5; j++) {
                int col = j * 16 + c;
                if (col >= 20 && col < 69) {
#pragma unroll
                    for (int rr = 0; rr < 4; rr++) {
                        int m = mbase + rr;
                        if (m < 20)
                            ori_w[(((size_t)b * NH + h) * PLEN + m) * NWIN + (col - 20)] = s[j][rr];
                    }
                }
            }
        }
        // scale + padded bias/mask table: branch-free
#pragma unroll
        for (int j = 0; j < 5; j++) {
#pragma unroll
            for (int rr = 0; rr < 4; rr++) {
                int m = mbase + rr;
                s[j][rr] = fmaf(s[j][rr], SCALE_F, bmw[m * 80 + j * 16 + c]);
            }
        }
        // in-register softmax (row = quad*4+rr, 16 lanes share a row)
#pragma unroll
        for (int rr = 0; rr < 4; rr++) {
            float mx = fmaxf(fmaxf(fmaxf(s[0][rr], s[1][rr]), fmaxf(s[2][rr], s[3][rr])), s[4][rr]);
            mx = fmaxf(mx, __shfl_xor(mx, 1));
            mx = fmaxf(mx, __shfl_xor(mx, 2));
            mx = fmaxf(mx, __shfl_xor(mx, 4));
            mx = fmaxf(mx, __shfl_xor(mx, 8));
            float e0 = __expf(s[0][rr] - mx), e1 = __expf(s[1][rr] - mx), e2 = __expf(s[2][rr] - mx);
            float e3 = __expf(s[3][rr] - mx), e4 = __expf(s[4][rr] - mx);
            float sum = e0 + e1 + e2 + e3 + e4;
            sum += __shfl_xor(sum, 1);
            sum += __shfl_xor(sum, 2);
            sum += __shfl_xor(sum, 4);
            sum += __shfl_xor(sum, 8);
            float inv = 1.f / sum;
            int mrow = quad * 4 + rr;
            int xw = (mrow & 7) << 3;
            Ps[h][mrow][(c) ^ xw]      = f2b(e0 * inv);
            Ps[h][mrow][(16 + c) ^ xw] = f2b(e1 * inv);
            Ps[h][mrow][(32 + c) ^ xw] = f2b(e2 * inv);
            Ps[h][mrow][(48 + c) ^ xw] = f2b(e3 * inv);
            Ps[h][mrow][(64 + c) ^ xw] = f2b(e4 * inv);
        }
        // PV for this tile (wave-private Ps; no barrier needed)
#pragma unroll
        for (int dt = 0; dt < 2; dt++) {
            f32x4 o = {0.f, 0.f, 0.f, 0.f};
#pragma unroll
            for (int kc = 0; kc < 3; kc++) {
                bf16x8 pa = *(const bf16x8*)&Ps[h][c][(kc * 32 + quad * 8) ^ xk_rd];
                o = __builtin_amdgcn_mfma_f32_16x16x32_bf16(pa, vf[dt][kc], o, 0, 0, 0);
            }
#pragma unroll
            for (int rr = 0; rr < 4; rr++) {
                int m = mbase + rr;
                if (m < 69)
                    attn_out[((size_t)b * NTOK + m) * CDIM + h * HD + dt * 16 + c] = f2b(o[rr]);
            }
        }
    }
}

// ---------- proj: 128x128 MFMA GEMM, LDS-staged f32 epilogue ----------
__global__ __launch_bounds__(256) void proj_kernel(
    const ushort_t* __restrict__ attn_out, const ushort_t* __restrict__ Wtp,
    const float* __restrict__ bproj,
    float* __restrict__ x_out, float* __restrict__ promptproj)
{
    __shared__ __align__(16) char smem[128 * 136 * 4];
    ushort_t (*As)[136] = (ushort_t(*)[136])smem;
    ushort_t (*Bs)[136] = (ushort_t(*)[136])(smem + 128 * 136 * 2);
    float (*Osf)[136] = (float(*)[136])smem;

    const int m0 = blockIdx.x * 128;
    const int tid = threadIdx.x;

    for (int it = tid; it < 128 * 16; it += 256) {
        int r = it >> 4, ch = it & 15;
        *(uint4*)&As[r][ch * 8] = *(const uint4*)(attn_out + (size_t)(m0 + r) * CDIM + ch * 8);
    }
    for (int it = tid; it < 128 * 16; it += 256) {
        int r = it >> 4, ch = it & 15;
        *(uint4*)&Bs[r][ch * 8] = *(const uint4*)(Wtp + (size_t)r * 128 + ch * 8);
    }
    __syncthreads();

    const int lane = tid & 63, wv = tid >> 6;
    const int wr = wv >> 1, wc = wv & 1;
    const int c = lane & 15, quad = lane >> 4;

    f32x4 acc[4][4];
#pragma unroll
    for (int i = 0; i < 4; i++)
#pragma unroll
        for (int j = 0; j < 4; j++) acc[i][j] = (f32x4){0.f, 0.f, 0.f, 0.f};

#pragma unroll
    for (int kc = 0; kc < 4; kc++) {
        bf16x8 a[4], b[4];
#pragma unroll
        for (int i = 0; i < 4; i++) a[i] = *(const bf16x8*)&As[wr * 64 + i * 16 + c][kc * 32 + quad * 8];
#pragma unroll
        for (int j = 0; j < 4; j++) b[j] = *(const bf16x8*)&Bs[wc * 64 + j * 16 + c][kc * 32 + quad * 8];
#pragma unroll
        for (int i = 0; i < 4; i++)
#pragma unroll
            for (int j = 0; j < 4; j++)
                acc[i][j] = __builtin_amdgcn_mfma_f32_16x16x32_bf16(a[i], b[j], acc[i][j], 0, 0, 0);
    }

    __syncthreads();
#pragma unroll
    for (int j = 0; j < 4; j++) {
        int col = wc * 64 + j * 16 + c;
        float bias = bproj[col];
#pragma unroll
        for (int i = 0; i < 4; i++) {
            int rl = wr * 64 + i * 16 + quad * 4;
#pragma unroll
            for (int rr = 0; rr < 4; rr++)
                Osf[rl + rr][col] = acc[i][j][rr] + bias;
        }
    }
    __syncthreads();

    for (int it = tid; it < 128 * 32; it += 256) {
        int r = it >> 5, ch = it & 31;
        float4 val = *(float4*)&Osf[r][ch * 4];
        int row = m0 + r;
        int bidx = row / NTOK, n = row - bidx * NTOK;
        if (n >= PLEN)
            *(float4*)&x_out[((size_t)bidx * NWIN + (n - PLEN)) * CDIM + ch * 4] = val;
        else
            *(float4*)&promptproj[((size_t)bidx * PLEN + n) * CDIM + ch * 4] = val;
    }
}

// ---------- prompt mean over 64 windows ----------
__global__ __launch_bounds__(256) void mean_kernel(
    const float* __restrict__ promptproj, float* __restrict__ prompts_out)
{
    int idx = blockIdx.x * 256 + threadIdx.x;
    if (idx >= BGRP * PLEN * CDIM) return;
    int c = idx & 127;
    int p = (idx >> 7) % PLEN;
    int bb = idx / (PLEN * CDIM);
    size_t base = (((size_t)bb * NW) * PLEN + p) * CDIM + c;
    float s = 0.f;
    for (int w = 0; w < NW; w++) s += promptproj[base + (size_t)w * (PLEN * CDIM)];
    prompts_out[idx] = s * (1.f / 64.f);
}

extern "C" void kernel_launch(void* const* d_in, const int* in_sizes, int n_in,
                              void* d_out, int out_size, void* d_ws, size_t ws_size,
                              hipStream_t stream)
{
    const float* x       = (const float*)d_in[0];
    const float* prompts = (const float*)d_in[1];
    const float* mask    = (const float*)d_in[2];
    const float* relb    = (const float*)d_in[3];
    const float* Wqkv    = (const float*)d_in[4];
    const float* bqkv    = (const float*)d_in[5];
    const float* Wproj   = (const float*)d_in[6];
    const float* bproj   = (const float*)d_in[7];

    float* out = (float*)d_out;
    float* x_out       = out;
    float* ori_w       = out + (size_t)B_TOT * NWIN * CDIM;
    float* prompts_out = ori_w + (size_t)B_TOT * NH * PLEN * NWIN;

    char* wsb = (char*)d_ws;
    size_t off = 0;
    const size_t winQKV = (size_t)WIN_ROWS * CDIM;
    const size_t pQKV   = (size_t)PROMPT_ROWS * CDIM;
    ushort_t* q_win = (ushort_t*)(wsb + off); off += winQKV * 2;
    ushort_t* k_win = (ushort_t*)(wsb + off); off += winQKV * 2;
    ushort_t* v_win = (ushort_t*)(wsb + off); off += winQKV * 2;
    ushort_t* q_p   = (ushort_t*)(wsb + off); off += pQKV * 2;
    ushort_t* k_p   = (ushort_t*)(wsb + off); off += pQKV * 2;
    ushort_t* v_p   = (ushort_t*)(wsb + off); off += pQKV * 2;
    ushort_t* attn_o = (ushort_t*)(wsb + off); off += (size_t)PROJ_ROWS * CDIM * 2;
    float* promptproj = (float*)(wsb + off); off += (size_t)B_TOT * PLEN * CDIM * 4;
    float* bm80 = (float*)(wsb + off); off += (size_t)NW * NH * 80 * 80 * 4;
    ushort_t* Wtq = (ushort_t*)(wsb + off); off += 384 * 128 * 2;
    ushort_t* Wtp = (ushort_t*)(wsb + off); off += 128 * 128 * 2;

    convw_kernel<<<256, 256, 0, stream>>>(Wqkv, Wproj, Wtq, Wtp);
    bm80_kernel<<<(NW * NH * 80 * 80) / 256, 256, 0, stream>>>(relb, mask, bm80);
    qkv_kernel<<<TOT_ROWS / 128, 256, 0, stream>>>(x, prompts, Wtq, bqkv,
                                                   q_win, k_win, v_win, q_p, k_p, v_p);
    attn_kernel<<<B_TOT, 256, 0, stream>>>(q_win, k_win, v_win, q_p, k_p, v_p,
                                           bm80, attn_o, ori_w);
    proj_kernel<<<PROJ_ROWS / 128, 256, 0, stream>>>(attn_o, Wtp, bproj, x_out, promptproj);
    mean_kernel<<<(BGRP * PLEN * CDIM + 255) / 256, 256, 0, stream>>>(promptproj, prompts_out);
}